// Round 1
// baseline (683.701 us; speedup 1.0000x reference)
//
#include <hip/hip_runtime.h>
#include <hip/hip_fp16.h>
#include <math.h>

#define N_NODES 100000
#define DIM 64
#define E_REL 1600000
#define E_QQ 1000000

#define NBUCK 196      // ceil(100000 / 512) node buckets of 512
#define BCAP 9216      // capacity per bucket; expected 8192, +11 sigma slack
#define CHUNK_E 2048   // edges per phase-1 block (smaller -> 782 blocks, better occupancy)
#define P1_BLOCKS ((E_REL + CHUNK_E - 1) / CHUNK_E)
#define AGG_BLOCKS 2048          // persistent grid-stride blocks for gather kernels
#define AGG_STRIDE (AGG_BLOCKS * 4)

// ---------------------------------------------------------------------------
// Phase 1: bin edges by dst-bucket (packed (dlocal<<17)|src). Out-degree via
// direct global atomics (replaces the whole src-side binning pass).
// ---------------------------------------------------------------------------
__global__ __launch_bounds__(256) void bin_edges(
    const int* __restrict__ src, const int* __restrict__ dst,
    int* __restrict__ gcur_d, int* __restrict__ odeg,
    unsigned* __restrict__ bin_d) {
  __shared__ int cd[NBUCK];
  int t = threadIdx.x;
  for (int i = t; i < NBUCK; i += 256) cd[i] = 0;
  __syncthreads();
  int e0 = blockIdx.x * CHUNK_E;
  int e1 = e0 + CHUNK_E;
  if (e1 > E_REL) e1 = E_REL;
  for (int e = e0 + t; e < e1; e += 256) {
    atomicAdd(&cd[dst[e] >> 9], 1);
    atomicAdd(&odeg[src[e]], 1);   // fire-and-forget, L2 atomic units
  }
  __syncthreads();
  for (int i = t; i < NBUCK; i += 256) {
    int c = cd[i];
    cd[i] = c > 0 ? atomicAdd(&gcur_d[i], c) : 0;
  }
  __syncthreads();
  for (int e = e0 + t; e < e1; e += 256) {
    int s = src[e];
    int d = dst[e];
    int bd = d >> 9;
    int pd = atomicAdd(&cd[bd], 1);
    if ((unsigned)pd < BCAP)
      bin_d[(size_t)bd * BCAP + pd] = (unsigned)(((d & 511) << 17) | s);
  }
}

// ---------------------------------------------------------------------------
// Phase 2: one block per dst-bucket (1024 threads): histogram -> scan ->
// compact per-node src lists + offs/deg. csrc = rsqrt(odeg) folded in.
// ---------------------------------------------------------------------------
__global__ __launch_bounds__(1024) void build_tables(
    const unsigned* __restrict__ bin_d, const int* __restrict__ gcur_d,
    const int* __restrict__ odeg, int* __restrict__ offs,
    int* __restrict__ degv, int* __restrict__ srclist,
    float* __restrict__ csrc) {
  __shared__ int cnt[512];
  __shared__ int off0[512];
  __shared__ int curv[512];
  __shared__ int ls[512];
  int t = threadIdx.x;
  int b = blockIdx.x;
  if (t < 512) cnt[t] = 0;
  __syncthreads();
  int n = gcur_d[b];
  if (n > BCAP) n = BCAP;
  const unsigned* be = bin_d + (size_t)b * BCAP;
  for (int i = t; i < n; i += 1024) atomicAdd(&cnt[be[i] >> 17], 1);
  __syncthreads();
  if (t < 512) ls[t] = cnt[t];
  __syncthreads();
  for (int off = 1; off < 512; off <<= 1) {
    int v = 0;
    if (t < 512 && t >= off) v = ls[t - off];
    __syncthreads();
    if (t < 512) ls[t] += v;
    __syncthreads();
  }
  if (t < 512) {
    int base = ls[t] - cnt[t];
    off0[t] = base;
    curv[t] = base;
  }
  __syncthreads();
  for (int i = t; i < n; i += 1024) {
    unsigned p = be[i];
    int pos = atomicAdd(&curv[p >> 17], 1);
    srclist[(size_t)b * BCAP + pos] = (int)(p & 0x1FFFF);
  }
  int node = (b << 9) + t;
  if (t < 512 && node < N_NODES) {
    offs[node] = b * BCAP + off0[t];
    degv[node] = cnt[t];
    int od = odeg[node];
    csrc[node] = od > 0 ? rsqrtf((float)od) : 0.0f;
  }
}

__device__ inline unsigned pack_h2(float a, float b) {
  __half2 h = __floats2half2_rn(a, b);
  return *reinterpret_cast<unsigned*>(&h);
}

// ---------------------------------------------------------------------------
// Y[row] = fp16( csrc[row] * (X[row] @ W) )   thread-per-row, W in LDS
// ---------------------------------------------------------------------------
__global__ __launch_bounds__(256) void gemm_in_h(
    const float* __restrict__ X, const float* __restrict__ W,
    const float* __restrict__ csrc, __half* __restrict__ Y) {
  __shared__ float Ws[64 * 64];
  for (int t = threadIdx.x; t < 64 * 64; t += 256) Ws[t] = W[t];
  __syncthreads();
  int row = blockIdx.x * 256 + threadIdx.x;
  if (row >= N_NODES) return;
  const float4* xr = (const float4*)(X + (size_t)row * 64);
  float acc[64];
#pragma unroll
  for (int j = 0; j < 64; j++) acc[j] = 0.0f;
#pragma unroll
  for (int k4 = 0; k4 < 16; k4++) {
    float4 xv = xr[k4];
    const float* w0 = &Ws[(k4 * 4 + 0) * 64];
    const float* w1 = &Ws[(k4 * 4 + 1) * 64];
    const float* w2 = &Ws[(k4 * 4 + 2) * 64];
    const float* w3 = &Ws[(k4 * 4 + 3) * 64];
#pragma unroll
    for (int j = 0; j < 64; j++)
      acc[j] += xv.x * w0[j] + xv.y * w1[j] + xv.z * w2[j] + xv.w * w3[j];
  }
  float s = csrc[row];
  uint4* yr = (uint4*)(Y + (size_t)row * 64);
#pragma unroll
  for (int j8 = 0; j8 < 8; j8++) {
    uint4 u;
    u.x = pack_h2(s * acc[j8 * 8 + 0], s * acc[j8 * 8 + 1]);
    u.y = pack_h2(s * acc[j8 * 8 + 2], s * acc[j8 * 8 + 3]);
    u.z = pack_h2(s * acc[j8 * 8 + 4], s * acc[j8 * 8 + 5]);
    u.w = pack_h2(s * acc[j8 * 8 + 6], s * acc[j8 * 8 + 7]);
    yr[j8] = u;
  }
}

// ---------------------------------------------------------------------------
// Packed-half accumulate: w holds 2 fp16 features; v_dot2_f32_f16 with masks
// (1,0)/(0,1) accumulates each into its f32 lane accumulator — 2 VALU ops
// per word vs 4 for cvt+cvt+add+add, identical f32 numerics (x*1.0 exact).
// ---------------------------------------------------------------------------
typedef _Float16 half2r __attribute__((ext_vector_type(2)));

__device__ inline void dacc(unsigned w, float& a, float& b) {
  half2r v = __builtin_bit_cast(half2r, w);
  const half2r m10 = {(_Float16)1.0f, (_Float16)0.0f};
  const half2r m01 = {(_Float16)0.0f, (_Float16)1.0f};
  a = __builtin_amdgcn_fdot2(v, m10, a, false);
  b = __builtin_amdgcn_fdot2(v, m01, b, false);
}

// ---------------------------------------------------------------------------
// Quad-edge aggregation core, 16 edges per main iteration: wave = 1 node,
// lanes split 4 (edge slot q) x 16 (feature quad l). 4 independent uint2
// loads in flight per lane per iteration; dot2-masked accumulation.
// ---------------------------------------------------------------------------
__device__ inline float4 agg_quad(const __half* __restrict__ Y, int beg,
                                  int deg, const int* __restrict__ srclist,
                                  int lane, int l, int q) {
  float4 a0 = make_float4(0.f, 0.f, 0.f, 0.f);
  float4 a1 = make_float4(0.f, 0.f, 0.f, 0.f);
  const __half* Yl = Y + 4 * l;
  for (int base = 0; base < deg; base += 64) {
    int chunk = deg - base;
    if (chunk > 64) chunk = 64;
    int sv = (base + lane < deg) ? srclist[beg + base + lane] : 0;
    int nq16 = chunk & ~15;
    for (int j = 0; j < nq16; j += 16) {
      int s0 = __shfl(sv, j + q);
      int s1 = __shfl(sv, j + 4 + q);
      int s2 = __shfl(sv, j + 8 + q);
      int s3 = __shfl(sv, j + 12 + q);
      uint2 u0 = *(const uint2*)(Yl + (size_t)s0 * 64);
      uint2 u1 = *(const uint2*)(Yl + (size_t)s1 * 64);
      uint2 u2 = *(const uint2*)(Yl + (size_t)s2 * 64);
      uint2 u3 = *(const uint2*)(Yl + (size_t)s3 * 64);
      dacc(u0.x, a0.x, a0.y); dacc(u0.y, a0.z, a0.w);
      dacc(u1.x, a1.x, a1.y); dacc(u1.y, a1.z, a1.w);
      dacc(u2.x, a0.x, a0.y); dacc(u2.y, a0.z, a0.w);
      dacc(u3.x, a1.x, a1.y); dacc(u3.y, a1.z, a1.w);
    }
    // tail: up to 15 edges via 4 predicated quad steps
    int jt = nq16 + q;
#pragma unroll
    for (int ts = 0; ts < 4; ts++) {
      int jj = jt + 4 * ts;
      int s = __shfl(sv, jj & 63);
      if (jj < chunk) {
        uint2 u = *(const uint2*)(Yl + (size_t)s * 64);
        if (ts & 1) { dacc(u.x, a1.x, a1.y); dacc(u.y, a1.z, a1.w); }
        else        { dacc(u.x, a0.x, a0.y); dacc(u.y, a0.z, a0.w); }
      }
    }
  }
  a0.x += a1.x; a0.y += a1.y; a0.z += a1.z; a0.w += a1.w;
  a0.x += __shfl_xor(a0.x, 16); a0.y += __shfl_xor(a0.y, 16);
  a0.z += __shfl_xor(a0.z, 16); a0.w += __shfl_xor(a0.w, 16);
  a0.x += __shfl_xor(a0.x, 32); a0.y += __shfl_xor(a0.y, 32);
  a0.z += __shfl_xor(a0.z, 32); a0.w += __shfl_xor(a0.w, 32);
  return a0;
}

// ---------------------------------------------------------------------------
// Fused: conv1 aggregation + epilogue + conv2 input GEMM. Persistent
// grid-stride blocks: W1 staged ONCE per block (was once per 4 nodes).
// W1 transposed in LDS with 16B-chunk XOR swizzle -> 16x ds_read_b128/node
// instead of 64x ds_read_b32, conflict-minimal.
// ---------------------------------------------------------------------------
__global__ __launch_bounds__(256) void gather_mid(
    const __half* __restrict__ Y, const int* __restrict__ offs,
    const int* __restrict__ degv, const int* __restrict__ srclist,
    const float* __restrict__ b0, const float* __restrict__ csrc,
    const float* __restrict__ W1, __half* __restrict__ Y2) {
  __shared__ float WsT[64 * 64];  // [out][k], 16B chunk c = k4 ^ (out&7)
  __shared__ float hs[4][64];
  for (int i = threadIdx.x; i < 64 * 64; i += 256) {
    int k = i >> 6, o = i & 63;
    int c = (k >> 2) ^ (o & 7);
    WsT[o * 64 + (c << 2) + (k & 3)] = W1[i];
  }
  __syncthreads();
  int lane = threadIdx.x & 63;
  int wslot = threadIdx.x >> 6;
  int l = lane & 15, q = lane >> 4;
  float4 bv = ((const float4*)b0)[l];
  for (int wid = blockIdx.x * 4 + wslot; wid < N_NODES; wid += AGG_STRIDE) {
    int beg = offs[wid];
    int deg = degv[wid];
    float4 acc = agg_quad(Y, beg, deg, srclist, lane, l, q);
    float cd = deg > 0 ? rsqrtf((float)deg) : 0.0f;
    float4 h;
    h.x = fmaxf(acc.x * cd + bv.x, 0.0f);
    h.y = fmaxf(acc.y * cd + bv.y, 0.0f);
    h.z = fmaxf(acc.z * cd + bv.z, 0.0f);
    h.w = fmaxf(acc.w * cd + bv.w, 0.0f);
    if (lane < 16) *((float4*)&hs[wslot][4 * l]) = h;
    // same-wave LDS RAW: in-order DS pipe, no barrier needed
    float acc2 = 0.0f;
#pragma unroll
    for (int k4 = 0; k4 < 16; k4++) {
      float4 hv = *((const float4*)&hs[wslot][4 * k4]);
      float4 w = *((const float4*)&WsT[lane * 64 + ((k4 ^ (lane & 7)) << 2)]);
      acc2 += hv.x * w.x + hv.y * w.y + hv.z * w.z + hv.w * w.w;
    }
    Y2[(size_t)wid * 64 + lane] = __float2half(csrc[wid] * acc2);
  }
}

// ---------------------------------------------------------------------------
// Final aggregation + epilogue into z (fp32 output), grid-stride persistent.
// MODE 0: z = relu(...)
// MODE 1: z -= relu(...), and emit uv[node] = {z.Wc_top(2), z.Wc_bot(2)}
// ---------------------------------------------------------------------------
template <int MODE>
__global__ __launch_bounds__(256) void gather_fin(
    const __half* __restrict__ Y2, const int* __restrict__ offs,
    const int* __restrict__ degv, const int* __restrict__ srclist,
    const float* __restrict__ b1, float* __restrict__ z,
    float* __restrict__ uv, const float* __restrict__ Wc) {
  __shared__ float Wcs[256];
  if (MODE == 1) {
    Wcs[threadIdx.x] = Wc[threadIdx.x];
    __syncthreads();
  }
  int lane = threadIdx.x & 63;
  int wslot = threadIdx.x >> 6;
  int l = lane & 15, q = lane >> 4;
  float4 bv = ((const float4*)b1)[l];
  for (int wid = blockIdx.x * 4 + wslot; wid < N_NODES; wid += AGG_STRIDE) {
    int beg = offs[wid];
    int deg = degv[wid];
    float4 acc = agg_quad(Y2, beg, deg, srclist, lane, l, q);
    float cd = deg > 0 ? rsqrtf((float)deg) : 0.0f;
    float4 v;
    v.x = fmaxf(acc.x * cd + bv.x, 0.0f);
    v.y = fmaxf(acc.y * cd + bv.y, 0.0f);
    v.z = fmaxf(acc.z * cd + bv.z, 0.0f);
    v.w = fmaxf(acc.w * cd + bv.w, 0.0f);
    float* zrow = z + (size_t)wid * 64 + 4 * l;
    if (MODE == 0) {
      if (lane < 16) *((float4*)zrow) = v;
    } else {
      float4 zo = *((const float4*)zrow);
      float4 r;
      r.x = zo.x - v.x; r.y = zo.y - v.y; r.z = zo.z - v.z; r.w = zo.w - v.w;
      if (lane < 16) *((float4*)zrow) = r;
      float pu0 = r.x * Wcs[(4 * l + 0) * 2 + 0] + r.y * Wcs[(4 * l + 1) * 2 + 0] +
                  r.z * Wcs[(4 * l + 2) * 2 + 0] + r.w * Wcs[(4 * l + 3) * 2 + 0];
      float pu1 = r.x * Wcs[(4 * l + 0) * 2 + 1] + r.y * Wcs[(4 * l + 1) * 2 + 1] +
                  r.z * Wcs[(4 * l + 2) * 2 + 1] + r.w * Wcs[(4 * l + 3) * 2 + 1];
      float pv0 = r.x * Wcs[(64 + 4 * l + 0) * 2 + 0] + r.y * Wcs[(64 + 4 * l + 1) * 2 + 0] +
                  r.z * Wcs[(64 + 4 * l + 2) * 2 + 0] + r.w * Wcs[(64 + 4 * l + 3) * 2 + 0];
      float pv1 = r.x * Wcs[(64 + 4 * l + 0) * 2 + 1] + r.y * Wcs[(64 + 4 * l + 1) * 2 + 1] +
                  r.z * Wcs[(64 + 4 * l + 2) * 2 + 1] + r.w * Wcs[(64 + 4 * l + 3) * 2 + 1];
#pragma unroll
      for (int o = 1; o < 16; o <<= 1) {
        pu0 += __shfl_xor(pu0, o);
        pu1 += __shfl_xor(pu1, o);
        pv0 += __shfl_xor(pv0, o);
        pv1 += __shfl_xor(pv1, o);
      }
      if (lane == 0) {
        float4 o4 = make_float4(pu0, pu1, pv0, pv1);
        *((float4*)(uv + (size_t)wid * 4)) = o4;
      }
    }
  }
}

// ---------------------------------------------------------------------------
// probs[e] = sigmoid(u(s) + v(d) + bc)  — factorized classifier
// ---------------------------------------------------------------------------
__global__ __launch_bounds__(256) void classify_kernel(
    const float* __restrict__ uv, const int* __restrict__ ei,
    const float* __restrict__ bc, float* __restrict__ out) {
  int e = blockIdx.x * 256 + threadIdx.x;
  if (e >= E_QQ) return;
  int s = ei[e];
  int d = ei[E_QQ + e];
  float4 us = *((const float4*)(uv + (size_t)s * 4));
  float4 vd = *((const float4*)(uv + (size_t)d * 4));
  float l0 = us.x + vd.z + bc[0];
  float l1 = us.y + vd.w + bc[1];
  float2 o;
  o.x = 1.0f / (1.0f + __expf(-l0));
  o.y = 1.0f / (1.0f + __expf(-l1));
  *((float2*)(out + (size_t)e * 2)) = o;
}

extern "C" void kernel_launch(void* const* d_in, const int* in_sizes, int n_in,
                              void* d_out, int out_size, void* d_ws,
                              size_t ws_size, hipStream_t stream) {
  const float* x   = (const float*)d_in[0];
  const float* W0p = (const float*)d_in[1];
  const float* b0p = (const float*)d_in[2];
  const float* W0n = (const float*)d_in[3];
  const float* b0n = (const float*)d_in[4];
  const float* W1p = (const float*)d_in[5];
  const float* b1p = (const float*)d_in[6];
  const float* W1n = (const float*)d_in[7];
  const float* b1n = (const float*)d_in[8];
  const float* Wc  = (const float*)d_in[9];
  const float* bc  = (const float*)d_in[10];
  const int* sp = (const int*)d_in[11];
  const int* dp = (const int*)d_in[12];
  const int* sn = (const int*)d_in[13];
  const int* dn = (const int*)d_in[14];
  const int* ei = (const int*)d_in[15];

  // workspace layout (~45 MB)
  float* csrc_p = (float*)d_ws;                       // N
  float* csrc_n = csrc_p + N_NODES;                   // N
  int* offs_p = (int*)(csrc_n + N_NODES);             // N
  int* deg_p  = offs_p + N_NODES;                     // N
  int* offs_n = deg_p + N_NODES;                      // N
  int* deg_n  = offs_n + N_NODES;                     // N
  float* uv   = (float*)(deg_n + N_NODES);            // 4N
  int* odeg   = (int*)(uv + 4 * N_NODES);             // N
  int* gcur   = odeg + N_NODES;                       // NBUCK (+pad)
  unsigned* bin_d = (unsigned*)(gcur + NBUCK + 4);    // NBUCK*BCAP
  int* srclist = (int*)(bin_d + (size_t)NBUCK * BCAP);       // NBUCK*BCAP
  __half* A = (__half*)(srclist + (size_t)NBUCK * BCAP);     // N*64 fp16
  __half* B = A + (size_t)N_NODES * 64;                      // N*64 fp16

  float* z     = (float*)d_out;                   // N*64 fp32
  float* probs = z + (size_t)N_NODES * 64;        // E_Q*2 fp32

  const int gemmGrid = (N_NODES + 255) / 256;

  // ---- POS relation ----
  hipMemsetAsync(odeg, 0, (N_NODES + NBUCK + 4) * sizeof(int), stream);
  bin_edges<<<P1_BLOCKS, 256, 0, stream>>>(sp, dp, gcur, odeg, bin_d);
  build_tables<<<NBUCK, 1024, 0, stream>>>(bin_d, gcur, odeg, offs_p, deg_p,
                                           srclist, csrc_p);
  gemm_in_h<<<gemmGrid, 256, 0, stream>>>(x, W0p, csrc_p, A);
  gather_mid<<<AGG_BLOCKS, 256, 0, stream>>>(A, offs_p, deg_p, srclist, b0p,
                                             csrc_p, W1p, B);
  gather_fin<0><<<AGG_BLOCKS, 256, 0, stream>>>(B, offs_p, deg_p, srclist, b1p,
                                                z, uv, Wc);

  // ---- NEG relation ---- (bins/srclist reused; pos consumers done)
  hipMemsetAsync(odeg, 0, (N_NODES + NBUCK + 4) * sizeof(int), stream);
  bin_edges<<<P1_BLOCKS, 256, 0, stream>>>(sn, dn, gcur, odeg, bin_d);
  build_tables<<<NBUCK, 1024, 0, stream>>>(bin_d, gcur, odeg, offs_n, deg_n,
                                           srclist, csrc_n);
  gemm_in_h<<<gemmGrid, 256, 0, stream>>>(x, W0n, csrc_n, A);
  gather_mid<<<AGG_BLOCKS, 256, 0, stream>>>(A, offs_n, deg_n, srclist, b0n,
                                             csrc_n, W1n, B);
  gather_fin<1><<<AGG_BLOCKS, 256, 0, stream>>>(B, offs_n, deg_n, srclist, b1n,
                                                z, uv, Wc);

  // ---- classifier (factorized) ----
  classify_kernel<<<(E_QQ + 255) / 256, 256, 0, stream>>>(uv, ei, bc, probs);
}

// Round 3
// 588.964 us; speedup vs baseline: 1.1609x; 1.1609x over previous
//
#include <hip/hip_runtime.h>
#include <hip/hip_fp16.h>
#include <math.h>

#define N_NODES 100000
#define DIM 64
#define E_REL 1600000
#define E_QQ 1000000

#define NBUCK 196      // ceil(100000 / 512) node buckets of 512
#define BCAP 9216      // capacity per bucket; expected 8192, +11 sigma slack
#define CHUNK_E 4096   // edges per phase-1 block -> 391 blocks (occupancy)
#define P1_BLOCKS ((E_REL + CHUNK_E - 1) / CHUNK_E)
#define AGG_BLOCKS 2048          // persistent grid-stride blocks for gather kernels
#define AGG_STRIDE (AGG_BLOCKS * 4)

// ---------------------------------------------------------------------------
// Phase 1: bin edges by dst-bucket (packed (dlocal<<17)|src) and by src-bucket
// (raw src). Per-block LDS counts; ~2*NBUCK global atomics per block reserve
// space; placement via LDS cursors. int4-vectorized edge reads.
// ---------------------------------------------------------------------------
__global__ __launch_bounds__(256) void bin_edges(
    const int* __restrict__ src, const int* __restrict__ dst,
    int* __restrict__ gcur_d, int* __restrict__ gcur_s,
    unsigned* __restrict__ bin_d, unsigned* __restrict__ bin_s) {
  __shared__ int cd[NBUCK];
  __shared__ int cs[NBUCK];
  int t = threadIdx.x;
  for (int i = t; i < NBUCK; i += 256) { cd[i] = 0; cs[i] = 0; }
  __syncthreads();
  int e0 = blockIdx.x * CHUNK_E;
  int n = E_REL - e0;
  if (n > CHUNK_E) n = CHUNK_E;
  int n4 = n >> 2;  // chunk sizes (4096 / 2560 tail) are multiples of 4
  const int4* s4 = (const int4*)(src + e0);
  const int4* d4 = (const int4*)(dst + e0);
  for (int i = t; i < n4; i += 256) {
    int4 dv = d4[i];
    atomicAdd(&cd[dv.x >> 9], 1);
    atomicAdd(&cd[dv.y >> 9], 1);
    atomicAdd(&cd[dv.z >> 9], 1);
    atomicAdd(&cd[dv.w >> 9], 1);
    int4 sv = s4[i];
    atomicAdd(&cs[sv.x >> 9], 1);
    atomicAdd(&cs[sv.y >> 9], 1);
    atomicAdd(&cs[sv.z >> 9], 1);
    atomicAdd(&cs[sv.w >> 9], 1);
  }
  __syncthreads();
  for (int i = t; i < NBUCK; i += 256) {
    int c = cd[i];
    cd[i] = c > 0 ? atomicAdd(&gcur_d[i], c) : 0;
    c = cs[i];
    cs[i] = c > 0 ? atomicAdd(&gcur_s[i], c) : 0;
  }
  __syncthreads();
  for (int i = t; i < n4; i += 256) {
    int4 sv = s4[i];
    int4 dv = d4[i];
#pragma unroll
    for (int k = 0; k < 4; k++) {
      int s = (&sv.x)[k];
      int d = (&dv.x)[k];
      int bd = d >> 9;
      int bs = s >> 9;
      int pd = atomicAdd(&cd[bd], 1);
      int ps = atomicAdd(&cs[bs], 1);
      if ((unsigned)pd < BCAP)
        bin_d[(size_t)bd * BCAP + pd] = (unsigned)(((d & 511) << 17) | s);
      if ((unsigned)ps < BCAP)
        bin_s[(size_t)bs * BCAP + ps] = (unsigned)s;
    }
  }
}

// ---------------------------------------------------------------------------
// Phase 2 fused: blocks 0..NBUCK-1 build the dst-CSR (histogram -> scan ->
// compact per-node src lists + offs/deg); blocks NBUCK..2*NBUCK-1 build the
// src-degree norm table csrc = rsqrt(outdeg).
// ---------------------------------------------------------------------------
__global__ __launch_bounds__(256) void build_tables(
    const unsigned* __restrict__ bin_d, const int* __restrict__ gcur_d,
    const unsigned* __restrict__ bin_s, const int* __restrict__ gcur_s,
    int* __restrict__ offs, int* __restrict__ degv, int* __restrict__ srclist,
    float* __restrict__ csrc) {
  __shared__ int cnt[512];
  __shared__ int off0[512];
  __shared__ int curv[512];
  __shared__ int ls[256];
  int t = threadIdx.x;
  if (blockIdx.x >= NBUCK) {
    // ---- src histogram -> csrc ----
    int b = blockIdx.x - NBUCK;
    cnt[t] = 0;
    cnt[t + 256] = 0;
    __syncthreads();
    int n = gcur_s[b];
    if (n > BCAP) n = BCAP;
    const unsigned* be = bin_s + (size_t)b * BCAP;
    for (int i = t; i < n; i += 256) atomicAdd(&cnt[be[i] & 511], 1);
    __syncthreads();
    int node0 = b << 9;
    for (int i = t; i < 512; i += 256) {
      int node = node0 + i;
      if (node < N_NODES) {
        int d = cnt[i];
        csrc[node] = d > 0 ? rsqrtf((float)d) : 0.0f;
      }
    }
    return;
  }
  // ---- dst CSR ----
  int b = blockIdx.x;
  cnt[t] = 0;
  cnt[t + 256] = 0;
  __syncthreads();
  int n = gcur_d[b];
  if (n > BCAP) n = BCAP;
  const unsigned* be = bin_d + (size_t)b * BCAP;
  for (int i = t; i < n; i += 256) atomicAdd(&cnt[be[i] >> 17], 1);
  __syncthreads();
  int c0 = cnt[2 * t], c1 = cnt[2 * t + 1];
  ls[t] = c0 + c1;
  __syncthreads();
  for (int off = 1; off < 256; off <<= 1) {
    int v = (t >= off) ? ls[t - off] : 0;
    __syncthreads();
    ls[t] += v;
    __syncthreads();
  }
  int base = ls[t] - (c0 + c1);
  off0[2 * t] = base;
  off0[2 * t + 1] = base + c0;
  curv[2 * t] = base;
  curv[2 * t + 1] = base + c0;
  __syncthreads();
  for (int i = t; i < n; i += 256) {
    unsigned p = be[i];
    int dl = p >> 17;
    int pos = atomicAdd(&curv[dl], 1);
    srclist[(size_t)b * BCAP + pos] = (int)(p & 0x1FFFF);
  }
  __syncthreads();
  int node0 = b << 9;
  for (int i = t; i < 512; i += 256) {
    int node = node0 + i;
    if (node < N_NODES) {
      offs[node] = b * BCAP + off0[i];
      degv[node] = cnt[i];
    }
  }
}

__device__ inline unsigned pack_h2(float a, float b) {
  __half2 h = __floats2half2_rn(a, b);
  return *reinterpret_cast<unsigned*>(&h);
}

// ---------------------------------------------------------------------------
// Y[row] = fp16( csrc[row] * (X[row] @ W) )   thread-per-row, W in LDS
// ---------------------------------------------------------------------------
__global__ __launch_bounds__(256) void gemm_in_h(
    const float* __restrict__ X, const float* __restrict__ W,
    const float* __restrict__ csrc, __half* __restrict__ Y) {
  __shared__ float Ws[64 * 64];
  for (int t = threadIdx.x; t < 64 * 64; t += 256) Ws[t] = W[t];
  __syncthreads();
  int row = blockIdx.x * 256 + threadIdx.x;
  if (row >= N_NODES) return;
  const float4* xr = (const float4*)(X + (size_t)row * 64);
  float acc[64];
#pragma unroll
  for (int j = 0; j < 64; j++) acc[j] = 0.0f;
#pragma unroll
  for (int k4 = 0; k4 < 16; k4++) {
    float4 xv = xr[k4];
    const float* w0 = &Ws[(k4 * 4 + 0) * 64];
    const float* w1 = &Ws[(k4 * 4 + 1) * 64];
    const float* w2 = &Ws[(k4 * 4 + 2) * 64];
    const float* w3 = &Ws[(k4 * 4 + 3) * 64];
#pragma unroll
    for (int j = 0; j < 64; j++)
      acc[j] += xv.x * w0[j] + xv.y * w1[j] + xv.z * w2[j] + xv.w * w3[j];
  }
  float s = csrc[row];
  uint4* yr = (uint4*)(Y + (size_t)row * 64);
#pragma unroll
  for (int j8 = 0; j8 < 8; j8++) {
    uint4 u;
    u.x = pack_h2(s * acc[j8 * 8 + 0], s * acc[j8 * 8 + 1]);
    u.y = pack_h2(s * acc[j8 * 8 + 2], s * acc[j8 * 8 + 3]);
    u.z = pack_h2(s * acc[j8 * 8 + 4], s * acc[j8 * 8 + 5]);
    u.w = pack_h2(s * acc[j8 * 8 + 6], s * acc[j8 * 8 + 7]);
    yr[j8] = u;
  }
}

// ---------------------------------------------------------------------------
// Packed-half accumulate: w holds 2 fp16 features; v_dot2_f32_f16 with masks
// (1,0)/(0,1) accumulates each into its f32 lane accumulator — 2 VALU ops
// per word vs 4 for cvt+cvt+add+add, identical f32 numerics (x*1.0 exact).
// ---------------------------------------------------------------------------
typedef _Float16 half2r __attribute__((ext_vector_type(2)));

__device__ inline void dacc(unsigned w, float& a, float& b) {
  half2r v = __builtin_bit_cast(half2r, w);
  const half2r m10 = {(_Float16)1.0f, (_Float16)0.0f};
  const half2r m01 = {(_Float16)0.0f, (_Float16)1.0f};
  a = __builtin_amdgcn_fdot2(v, m10, a, false);
  b = __builtin_amdgcn_fdot2(v, m01, b, false);
}

// ---------------------------------------------------------------------------
// Quad-edge aggregation core, 16 edges per main iteration: wave = 1 node,
// lanes split 4 (edge slot q) x 16 (feature quad l). 4 independent uint2
// loads in flight per lane per iteration; dot2-masked accumulation.
// ---------------------------------------------------------------------------
__device__ inline float4 agg_quad(const __half* __restrict__ Y, int beg,
                                  int deg, const int* __restrict__ srclist,
                                  int lane, int l, int q) {
  float4 a0 = make_float4(0.f, 0.f, 0.f, 0.f);
  float4 a1 = make_float4(0.f, 0.f, 0.f, 0.f);
  const __half* Yl = Y + 4 * l;
  for (int base = 0; base < deg; base += 64) {
    int chunk = deg - base;
    if (chunk > 64) chunk = 64;
    int sv = (base + lane < deg) ? srclist[beg + base + lane] : 0;
    int nq16 = chunk & ~15;
    for (int j = 0; j < nq16; j += 16) {
      int s0 = __shfl(sv, j + q);
      int s1 = __shfl(sv, j + 4 + q);
      int s2 = __shfl(sv, j + 8 + q);
      int s3 = __shfl(sv, j + 12 + q);
      uint2 u0 = *(const uint2*)(Yl + (size_t)s0 * 64);
      uint2 u1 = *(const uint2*)(Yl + (size_t)s1 * 64);
      uint2 u2 = *(const uint2*)(Yl + (size_t)s2 * 64);
      uint2 u3 = *(const uint2*)(Yl + (size_t)s3 * 64);
      dacc(u0.x, a0.x, a0.y); dacc(u0.y, a0.z, a0.w);
      dacc(u1.x, a1.x, a1.y); dacc(u1.y, a1.z, a1.w);
      dacc(u2.x, a0.x, a0.y); dacc(u2.y, a0.z, a0.w);
      dacc(u3.x, a1.x, a1.y); dacc(u3.y, a1.z, a1.w);
    }
    // tail: up to 15 edges via 4 predicated quad steps
    int jt = nq16 + q;
#pragma unroll
    for (int ts = 0; ts < 4; ts++) {
      int jj = jt + 4 * ts;
      int s = __shfl(sv, jj & 63);
      if (jj < chunk) {
        uint2 u = *(const uint2*)(Yl + (size_t)s * 64);
        if (ts & 1) { dacc(u.x, a1.x, a1.y); dacc(u.y, a1.z, a1.w); }
        else        { dacc(u.x, a0.x, a0.y); dacc(u.y, a0.z, a0.w); }
      }
    }
  }
  a0.x += a1.x; a0.y += a1.y; a0.z += a1.z; a0.w += a1.w;
  a0.x += __shfl_xor(a0.x, 16); a0.y += __shfl_xor(a0.y, 16);
  a0.z += __shfl_xor(a0.z, 16); a0.w += __shfl_xor(a0.w, 16);
  a0.x += __shfl_xor(a0.x, 32); a0.y += __shfl_xor(a0.y, 32);
  a0.z += __shfl_xor(a0.z, 32); a0.w += __shfl_xor(a0.w, 32);
  return a0;
}

// ---------------------------------------------------------------------------
// Fused: conv1 aggregation + epilogue + conv2 input GEMM. Persistent
// grid-stride blocks: W1 staged ONCE per block. W1 transposed in LDS with
// 16B-chunk XOR swizzle -> 16x ds_read_b128/node, broadcast/conflict-free.
// ---------------------------------------------------------------------------
__global__ __launch_bounds__(256) void gather_mid(
    const __half* __restrict__ Y, const int* __restrict__ offs,
    const int* __restrict__ degv, const int* __restrict__ srclist,
    const float* __restrict__ b0, const float* __restrict__ csrc,
    const float* __restrict__ W1, __half* __restrict__ Y2) {
  __shared__ float WsT[64 * 64];  // [out][k], 16B chunk c = k4 ^ (out&7)
  __shared__ float hs[4][64];
  for (int i = threadIdx.x; i < 64 * 64; i += 256) {
    int k = i >> 6, o = i & 63;
    int c = (k >> 2) ^ (o & 7);
    WsT[o * 64 + (c << 2) + (k & 3)] = W1[i];
  }
  __syncthreads();
  int lane = threadIdx.x & 63;
  int wslot = threadIdx.x >> 6;
  int l = lane & 15, q = lane >> 4;
  float4 bv = ((const float4*)b0)[l];
  for (int wid = blockIdx.x * 4 + wslot; wid < N_NODES; wid += AGG_STRIDE) {
    int beg = offs[wid];
    int deg = degv[wid];
    float4 acc = agg_quad(Y, beg, deg, srclist, lane, l, q);
    float cd = deg > 0 ? rsqrtf((float)deg) : 0.0f;
    float4 h;
    h.x = fmaxf(acc.x * cd + bv.x, 0.0f);
    h.y = fmaxf(acc.y * cd + bv.y, 0.0f);
    h.z = fmaxf(acc.z * cd + bv.z, 0.0f);
    h.w = fmaxf(acc.w * cd + bv.w, 0.0f);
    if (lane < 16) *((float4*)&hs[wslot][4 * l]) = h;
    // same-wave LDS RAW: in-order DS pipe, no barrier needed
    float acc2 = 0.0f;
#pragma unroll
    for (int k4 = 0; k4 < 16; k4++) {
      float4 hv = *((const float4*)&hs[wslot][4 * k4]);
      float4 w = *((const float4*)&WsT[lane * 64 + ((k4 ^ (lane & 7)) << 2)]);
      acc2 += hv.x * w.x + hv.y * w.y + hv.z * w.z + hv.w * w.w;
    }
    Y2[(size_t)wid * 64 + lane] = __float2half(csrc[wid] * acc2);
  }
}

// ---------------------------------------------------------------------------
// Final aggregation + epilogue into z (fp32 output), grid-stride persistent.
// MODE 0: z = relu(...)
// MODE 1: z -= relu(...), and emit uv[node] = {z.Wc_top(2), z.Wc_bot(2)}
// ---------------------------------------------------------------------------
template <int MODE>
__global__ __launch_bounds__(256) void gather_fin(
    const __half* __restrict__ Y2, const int* __restrict__ offs,
    const int* __restrict__ degv, const int* __restrict__ srclist,
    const float* __restrict__ b1, float* __restrict__ z,
    float* __restrict__ uv, const float* __restrict__ Wc) {
  __shared__ float Wcs[256];
  if (MODE == 1) {
    Wcs[threadIdx.x] = Wc[threadIdx.x];
    __syncthreads();
  }
  int lane = threadIdx.x & 63;
  int wslot = threadIdx.x >> 6;
  int l = lane & 15, q = lane >> 4;
  float4 bv = ((const float4*)b1)[l];
  for (int wid = blockIdx.x * 4 + wslot; wid < N_NODES; wid += AGG_STRIDE) {
    int beg = offs[wid];
    int deg = degv[wid];
    float4 acc = agg_quad(Y2, beg, deg, srclist, lane, l, q);
    float cd = deg > 0 ? rsqrtf((float)deg) : 0.0f;
    float4 v;
    v.x = fmaxf(acc.x * cd + bv.x, 0.0f);
    v.y = fmaxf(acc.y * cd + bv.y, 0.0f);
    v.z = fmaxf(acc.z * cd + bv.z, 0.0f);
    v.w = fmaxf(acc.w * cd + bv.w, 0.0f);
    float* zrow = z + (size_t)wid * 64 + 4 * l;
    if (MODE == 0) {
      if (lane < 16) *((float4*)zrow) = v;
    } else {
      float4 zo = *((const float4*)zrow);
      float4 r;
      r.x = zo.x - v.x; r.y = zo.y - v.y; r.z = zo.z - v.z; r.w = zo.w - v.w;
      if (lane < 16) *((float4*)zrow) = r;
      float pu0 = r.x * Wcs[(4 * l + 0) * 2 + 0] + r.y * Wcs[(4 * l + 1) * 2 + 0] +
                  r.z * Wcs[(4 * l + 2) * 2 + 0] + r.w * Wcs[(4 * l + 3) * 2 + 0];
      float pu1 = r.x * Wcs[(4 * l + 0) * 2 + 1] + r.y * Wcs[(4 * l + 1) * 2 + 1] +
                  r.z * Wcs[(4 * l + 2) * 2 + 1] + r.w * Wcs[(4 * l + 3) * 2 + 1];
      float pv0 = r.x * Wcs[(64 + 4 * l + 0) * 2 + 0] + r.y * Wcs[(64 + 4 * l + 1) * 2 + 0] +
                  r.z * Wcs[(64 + 4 * l + 2) * 2 + 0] + r.w * Wcs[(64 + 4 * l + 3) * 2 + 0];
      float pv1 = r.x * Wcs[(64 + 4 * l + 0) * 2 + 1] + r.y * Wcs[(64 + 4 * l + 1) * 2 + 1] +
                  r.z * Wcs[(64 + 4 * l + 2) * 2 + 1] + r.w * Wcs[(64 + 4 * l + 3) * 2 + 1];
#pragma unroll
      for (int o = 1; o < 16; o <<= 1) {
        pu0 += __shfl_xor(pu0, o);
        pu1 += __shfl_xor(pu1, o);
        pv0 += __shfl_xor(pv0, o);
        pv1 += __shfl_xor(pv1, o);
      }
      if (lane == 0) {
        float4 o4 = make_float4(pu0, pu1, pv0, pv1);
        *((float4*)(uv + (size_t)wid * 4)) = o4;
      }
    }
  }
}

// ---------------------------------------------------------------------------
// probs[e] = sigmoid(u(s) + v(d) + bc)  — factorized classifier
// ---------------------------------------------------------------------------
__global__ __launch_bounds__(256) void classify_kernel(
    const float* __restrict__ uv, const int* __restrict__ ei,
    const float* __restrict__ bc, float* __restrict__ out) {
  int e = blockIdx.x * 256 + threadIdx.x;
  if (e >= E_QQ) return;
  int s = ei[e];
  int d = ei[E_QQ + e];
  float4 us = *((const float4*)(uv + (size_t)s * 4));
  float4 vd = *((const float4*)(uv + (size_t)d * 4));
  float l0 = us.x + vd.z + bc[0];
  float l1 = us.y + vd.w + bc[1];
  float2 o;
  o.x = 1.0f / (1.0f + __expf(-l0));
  o.y = 1.0f / (1.0f + __expf(-l1));
  *((float2*)(out + (size_t)e * 2)) = o;
}

extern "C" void kernel_launch(void* const* d_in, const int* in_sizes, int n_in,
                              void* d_out, int out_size, void* d_ws,
                              size_t ws_size, hipStream_t stream) {
  const float* x   = (const float*)d_in[0];
  const float* W0p = (const float*)d_in[1];
  const float* b0p = (const float*)d_in[2];
  const float* W0n = (const float*)d_in[3];
  const float* b0n = (const float*)d_in[4];
  const float* W1p = (const float*)d_in[5];
  const float* b1p = (const float*)d_in[6];
  const float* W1n = (const float*)d_in[7];
  const float* b1n = (const float*)d_in[8];
  const float* Wc  = (const float*)d_in[9];
  const float* bc  = (const float*)d_in[10];
  const int* sp = (const int*)d_in[11];
  const int* dp = (const int*)d_in[12];
  const int* sn = (const int*)d_in[13];
  const int* dn = (const int*)d_in[14];
  const int* ei = (const int*)d_in[15];

  // workspace layout (~53 MB)
  float* csrc_p = (float*)d_ws;                       // N
  float* csrc_n = csrc_p + N_NODES;                   // N
  int* offs_p = (int*)(csrc_n + N_NODES);             // N
  int* deg_p  = offs_p + N_NODES;                     // N
  int* offs_n = deg_p + N_NODES;                      // N
  int* deg_n  = offs_n + N_NODES;                     // N
  float* uv   = (float*)(deg_n + N_NODES);            // 4N
  int* gcur   = (int*)(uv + 4 * N_NODES);             // 2*NBUCK (+pad)
  unsigned* bin_d = (unsigned*)(gcur + 2 * NBUCK + 2);       // NBUCK*BCAP
  unsigned* bin_s = bin_d + (size_t)NBUCK * BCAP;            // NBUCK*BCAP
  int* srclist = (int*)(bin_s + (size_t)NBUCK * BCAP);       // NBUCK*BCAP
  __half* A = (__half*)(srclist + (size_t)NBUCK * BCAP);     // N*64 fp16
  __half* B = A + (size_t)N_NODES * 64;                      // N*64 fp16

  float* z     = (float*)d_out;                   // N*64 fp32
  float* probs = z + (size_t)N_NODES * 64;        // E_Q*2 fp32

  int* gcur_d = gcur;
  int* gcur_s = gcur + NBUCK;

  const int gemmGrid = (N_NODES + 255) / 256;

  // ---- POS relation ----
  hipMemsetAsync(gcur, 0, 2 * NBUCK * sizeof(int), stream);
  bin_edges<<<P1_BLOCKS, 256, 0, stream>>>(sp, dp, gcur_d, gcur_s, bin_d, bin_s);
  build_tables<<<2 * NBUCK, 256, 0, stream>>>(bin_d, gcur_d, bin_s, gcur_s,
                                              offs_p, deg_p, srclist, csrc_p);
  gemm_in_h<<<gemmGrid, 256, 0, stream>>>(x, W0p, csrc_p, A);
  gather_mid<<<AGG_BLOCKS, 256, 0, stream>>>(A, offs_p, deg_p, srclist, b0p,
                                             csrc_p, W1p, B);
  gather_fin<0><<<AGG_BLOCKS, 256, 0, stream>>>(B, offs_p, deg_p, srclist, b1p,
                                                z, uv, Wc);

  // ---- NEG relation ---- (bins/srclist reused; pos consumers done)
  hipMemsetAsync(gcur, 0, 2 * NBUCK * sizeof(int), stream);
  bin_edges<<<P1_BLOCKS, 256, 0, stream>>>(sn, dn, gcur_d, gcur_s, bin_d, bin_s);
  build_tables<<<2 * NBUCK, 256, 0, stream>>>(bin_d, gcur_d, bin_s, gcur_s,
                                              offs_n, deg_n, srclist, csrc_n);
  gemm_in_h<<<gemmGrid, 256, 0, stream>>>(x, W0n, csrc_n, A);
  gather_mid<<<AGG_BLOCKS, 256, 0, stream>>>(A, offs_n, deg_n, srclist, b0n,
                                             csrc_n, W1n, B);
  gather_fin<1><<<AGG_BLOCKS, 256, 0, stream>>>(B, offs_n, deg_n, srclist, b1n,
                                                z, uv, Wc);

  // ---- classifier (factorized) ----
  classify_kernel<<<(E_QQ + 255) / 256, 256, 0, stream>>>(uv, ei, bc, probs);
}

// Round 4
// 579.220 us; speedup vs baseline: 1.1804x; 1.0168x over previous
//
#include <hip/hip_runtime.h>
#include <hip/hip_fp16.h>
#include <math.h>

#define N_NODES 100000
#define DIM 64
#define E_REL 1600000
#define E_QQ 1000000

#define NBUCK 196      // ceil(100000 / 512) node buckets of 512
#define BCAP 9216      // capacity per bucket; expected 8192, +11 sigma slack
#define CHUNK_E 4096   // edges per phase-1 block -> 391 blocks (occupancy)
#define P1_BLOCKS ((E_REL + CHUNK_E - 1) / CHUNK_E)
#define AGG_BLOCKS 2048          // persistent grid-stride blocks for gather kernels
#define AGG_STRIDE (AGG_BLOCKS * 4)

// ---------------------------------------------------------------------------
// Phase 1: bin edges by dst-bucket (packed (dlocal<<17)|src) and by src-bucket
// (raw src). Per-block LDS counts; ~2*NBUCK global atomics per block reserve
// space; placement via LDS cursors. int4-vectorized edge reads.
// ---------------------------------------------------------------------------
__global__ __launch_bounds__(256) void bin_edges(
    const int* __restrict__ src, const int* __restrict__ dst,
    int* __restrict__ gcur_d, int* __restrict__ gcur_s,
    unsigned* __restrict__ bin_d, unsigned* __restrict__ bin_s) {
  __shared__ int cd[NBUCK];
  __shared__ int cs[NBUCK];
  int t = threadIdx.x;
  for (int i = t; i < NBUCK; i += 256) { cd[i] = 0; cs[i] = 0; }
  __syncthreads();
  int e0 = blockIdx.x * CHUNK_E;
  int n = E_REL - e0;
  if (n > CHUNK_E) n = CHUNK_E;
  int n4 = n >> 2;  // chunk sizes (4096 / 2560 tail) are multiples of 4
  const int4* s4 = (const int4*)(src + e0);
  const int4* d4 = (const int4*)(dst + e0);
  for (int i = t; i < n4; i += 256) {
    int4 dv = d4[i];
    atomicAdd(&cd[dv.x >> 9], 1);
    atomicAdd(&cd[dv.y >> 9], 1);
    atomicAdd(&cd[dv.z >> 9], 1);
    atomicAdd(&cd[dv.w >> 9], 1);
    int4 sv = s4[i];
    atomicAdd(&cs[sv.x >> 9], 1);
    atomicAdd(&cs[sv.y >> 9], 1);
    atomicAdd(&cs[sv.z >> 9], 1);
    atomicAdd(&cs[sv.w >> 9], 1);
  }
  __syncthreads();
  for (int i = t; i < NBUCK; i += 256) {
    int c = cd[i];
    cd[i] = c > 0 ? atomicAdd(&gcur_d[i], c) : 0;
    c = cs[i];
    cs[i] = c > 0 ? atomicAdd(&gcur_s[i], c) : 0;
  }
  __syncthreads();
  for (int i = t; i < n4; i += 256) {
    int4 sv = s4[i];
    int4 dv = d4[i];
#pragma unroll
    for (int k = 0; k < 4; k++) {
      int s = (&sv.x)[k];
      int d = (&dv.x)[k];
      int bd = d >> 9;
      int bs = s >> 9;
      int pd = atomicAdd(&cd[bd], 1);
      int ps = atomicAdd(&cs[bs], 1);
      if ((unsigned)pd < BCAP)
        bin_d[(size_t)bd * BCAP + pd] = (unsigned)(((d & 511) << 17) | s);
      if ((unsigned)ps < BCAP)
        bin_s[(size_t)bs * BCAP + ps] = (unsigned)s;
    }
  }
}

// ---------------------------------------------------------------------------
// Phase 2 fused: blocks 0..NBUCK-1 build the dst-CSR (histogram -> scan ->
// compact per-node src lists + offs/deg); blocks NBUCK..2*NBUCK-1 build the
// src-degree norm table csrc = rsqrt(outdeg).
// ---------------------------------------------------------------------------
__global__ __launch_bounds__(256) void build_tables(
    const unsigned* __restrict__ bin_d, const int* __restrict__ gcur_d,
    const unsigned* __restrict__ bin_s, const int* __restrict__ gcur_s,
    int* __restrict__ offs, int* __restrict__ degv, int* __restrict__ srclist,
    float* __restrict__ csrc) {
  __shared__ int cnt[512];
  __shared__ int off0[512];
  __shared__ int curv[512];
  __shared__ int ls[256];
  int t = threadIdx.x;
  if (blockIdx.x >= NBUCK) {
    // ---- src histogram -> csrc ----
    int b = blockIdx.x - NBUCK;
    cnt[t] = 0;
    cnt[t + 256] = 0;
    __syncthreads();
    int n = gcur_s[b];
    if (n > BCAP) n = BCAP;
    const unsigned* be = bin_s + (size_t)b * BCAP;
    for (int i = t; i < n; i += 256) atomicAdd(&cnt[be[i] & 511], 1);
    __syncthreads();
    int node0 = b << 9;
    for (int i = t; i < 512; i += 256) {
      int node = node0 + i;
      if (node < N_NODES) {
        int d = cnt[i];
        csrc[node] = d > 0 ? rsqrtf((float)d) : 0.0f;
      }
    }
    return;
  }
  // ---- dst CSR ----
  int b = blockIdx.x;
  cnt[t] = 0;
  cnt[t + 256] = 0;
  __syncthreads();
  int n = gcur_d[b];
  if (n > BCAP) n = BCAP;
  const unsigned* be = bin_d + (size_t)b * BCAP;
  for (int i = t; i < n; i += 256) atomicAdd(&cnt[be[i] >> 17], 1);
  __syncthreads();
  int c0 = cnt[2 * t], c1 = cnt[2 * t + 1];
  ls[t] = c0 + c1;
  __syncthreads();
  for (int off = 1; off < 256; off <<= 1) {
    int v = (t >= off) ? ls[t - off] : 0;
    __syncthreads();
    ls[t] += v;
    __syncthreads();
  }
  int base = ls[t] - (c0 + c1);
  off0[2 * t] = base;
  off0[2 * t + 1] = base + c0;
  curv[2 * t] = base;
  curv[2 * t + 1] = base + c0;
  __syncthreads();
  for (int i = t; i < n; i += 256) {
    unsigned p = be[i];
    int dl = p >> 17;
    int pos = atomicAdd(&curv[dl], 1);
    srclist[(size_t)b * BCAP + pos] = (int)(p & 0x1FFFF);
  }
  __syncthreads();
  int node0 = b << 9;
  for (int i = t; i < 512; i += 256) {
    int node = node0 + i;
    if (node < N_NODES) {
      offs[node] = b * BCAP + off0[i];
      degv[node] = cnt[i];
    }
  }
}

__device__ inline unsigned pack_h2(float a, float b) {
  __half2 h = __floats2half2_rn(a, b);
  return *reinterpret_cast<unsigned*>(&h);
}

// ---------------------------------------------------------------------------
// Y[row] = fp16( csrc[row] * (X[row] @ W) )   thread-per-row, W in LDS
// ---------------------------------------------------------------------------
__global__ __launch_bounds__(256) void gemm_in_h(
    const float* __restrict__ X, const float* __restrict__ W,
    const float* __restrict__ csrc, __half* __restrict__ Y) {
  __shared__ float Ws[64 * 64];
  for (int t = threadIdx.x; t < 64 * 64; t += 256) Ws[t] = W[t];
  __syncthreads();
  int row = blockIdx.x * 256 + threadIdx.x;
  if (row >= N_NODES) return;
  const float4* xr = (const float4*)(X + (size_t)row * 64);
  float acc[64];
#pragma unroll
  for (int j = 0; j < 64; j++) acc[j] = 0.0f;
#pragma unroll
  for (int k4 = 0; k4 < 16; k4++) {
    float4 xv = xr[k4];
    const float* w0 = &Ws[(k4 * 4 + 0) * 64];
    const float* w1 = &Ws[(k4 * 4 + 1) * 64];
    const float* w2 = &Ws[(k4 * 4 + 2) * 64];
    const float* w3 = &Ws[(k4 * 4 + 3) * 64];
#pragma unroll
    for (int j = 0; j < 64; j++)
      acc[j] += xv.x * w0[j] + xv.y * w1[j] + xv.z * w2[j] + xv.w * w3[j];
  }
  float s = csrc[row];
  uint4* yr = (uint4*)(Y + (size_t)row * 64);
#pragma unroll
  for (int j8 = 0; j8 < 8; j8++) {
    uint4 u;
    u.x = pack_h2(s * acc[j8 * 8 + 0], s * acc[j8 * 8 + 1]);
    u.y = pack_h2(s * acc[j8 * 8 + 2], s * acc[j8 * 8 + 3]);
    u.z = pack_h2(s * acc[j8 * 8 + 4], s * acc[j8 * 8 + 5]);
    u.w = pack_h2(s * acc[j8 * 8 + 6], s * acc[j8 * 8 + 7]);
    yr[j8] = u;
  }
}

// ---------------------------------------------------------------------------
// Packed-half accumulate: w holds 2 fp16 features; v_dot2_f32_f16 with masks
// (1,0)/(0,1) accumulates each into its f32 lane accumulator — 2 VALU ops
// per word vs 4 for cvt+cvt+add+add, identical f32 numerics (x*1.0 exact).
// ---------------------------------------------------------------------------
typedef _Float16 half2r __attribute__((ext_vector_type(2)));

__device__ inline void dacc(unsigned w, float& a, float& b) {
  half2r v = __builtin_bit_cast(half2r, w);
  const half2r m10 = {(_Float16)1.0f, (_Float16)0.0f};
  const half2r m01 = {(_Float16)0.0f, (_Float16)1.0f};
  a = __builtin_amdgcn_fdot2(v, m10, a, false);
  b = __builtin_amdgcn_fdot2(v, m01, b, false);
}

// ---------------------------------------------------------------------------
// Oct-edge aggregation core: wave = 1 node, lanes split 8 (edge slot q) x
// 8 (feature oct f, 16B). Per 16-edge step each lane issues TWO uint4 loads
// (half the load/addr/shuffle instructions of the 4x uint2 form) into two
// independent accumulator banks. Butterfly-reduce over q at the end; after
// it, EVERY lane holds the full sum for its feature oct.
// ---------------------------------------------------------------------------
__device__ inline void agg_oct(const __half* __restrict__ Y, int beg, int deg,
                               const int* __restrict__ srclist, int lane,
                               int f, int q, float* __restrict__ out) {
  float a[8], b[8];
#pragma unroll
  for (int i = 0; i < 8; i++) { a[i] = 0.0f; b[i] = 0.0f; }
  const __half* Yl = Y + 8 * f;
  for (int base = 0; base < deg; base += 64) {
    int chunk = deg - base;
    if (chunk > 64) chunk = 64;
    int sv = (base + lane < deg) ? srclist[beg + base + lane] : 0;
    int nq16 = chunk & ~15;
    for (int j = 0; j < nq16; j += 16) {
      int s0 = __shfl(sv, j + q);
      int s1 = __shfl(sv, j + 8 + q);
      uint4 u0 = *(const uint4*)(Yl + (size_t)s0 * 64);
      uint4 u1 = *(const uint4*)(Yl + (size_t)s1 * 64);
      dacc(u0.x, a[0], a[1]); dacc(u0.y, a[2], a[3]);
      dacc(u0.z, a[4], a[5]); dacc(u0.w, a[6], a[7]);
      dacc(u1.x, b[0], b[1]); dacc(u1.y, b[2], b[3]);
      dacc(u1.z, b[4], b[5]); dacc(u1.w, b[6], b[7]);
    }
    // tail: up to 15 edges via 2 predicated oct steps
    int j0 = nq16 + q;
    int j1 = nq16 + 8 + q;
    int s0 = __shfl(sv, j0 & 63);
    int s1 = __shfl(sv, j1 & 63);
    if (j0 < chunk) {
      uint4 u = *(const uint4*)(Yl + (size_t)s0 * 64);
      dacc(u.x, a[0], a[1]); dacc(u.y, a[2], a[3]);
      dacc(u.z, a[4], a[5]); dacc(u.w, a[6], a[7]);
    }
    if (j1 < chunk) {
      uint4 u = *(const uint4*)(Yl + (size_t)s1 * 64);
      dacc(u.x, b[0], b[1]); dacc(u.y, b[2], b[3]);
      dacc(u.z, b[4], b[5]); dacc(u.w, b[6], b[7]);
    }
  }
#pragma unroll
  for (int i = 0; i < 8; i++) {
    float v = a[i] + b[i];
    v += __shfl_xor(v, 8);
    v += __shfl_xor(v, 16);
    v += __shfl_xor(v, 32);
    out[i] = v;
  }
}

// ---------------------------------------------------------------------------
// Fused: conv1 aggregation + epilogue + conv2 input GEMM. Persistent
// grid-stride blocks: W1 staged ONCE per block. W1 transposed in LDS with
// 16B-chunk XOR swizzle -> 16x ds_read_b128/node, broadcast/conflict-free.
// ---------------------------------------------------------------------------
__global__ __launch_bounds__(256) void gather_mid(
    const __half* __restrict__ Y, const int* __restrict__ offs,
    const int* __restrict__ degv, const int* __restrict__ srclist,
    const float* __restrict__ b0, const float* __restrict__ csrc,
    const float* __restrict__ W1, __half* __restrict__ Y2) {
  __shared__ float WsT[64 * 64];  // [out][k], 16B chunk c = k4 ^ (out&7)
  __shared__ float hs[4][64];
  for (int i = threadIdx.x; i < 64 * 64; i += 256) {
    int k = i >> 6, o = i & 63;
    int c = (k >> 2) ^ (o & 7);
    WsT[o * 64 + (c << 2) + (k & 3)] = W1[i];
  }
  __syncthreads();
  int lane = threadIdx.x & 63;
  int wslot = threadIdx.x >> 6;
  int f = lane & 7, q = lane >> 3;
  float4 bv0 = ((const float4*)b0)[2 * f];
  float4 bv1 = ((const float4*)b0)[2 * f + 1];
  for (int wid = blockIdx.x * 4 + wslot; wid < N_NODES; wid += AGG_STRIDE) {
    int beg = offs[wid];
    int deg = degv[wid];
    float acc[8];
    agg_oct(Y, beg, deg, srclist, lane, f, q, acc);
    float cd = deg > 0 ? rsqrtf((float)deg) : 0.0f;
    float4 h0, h1;
    h0.x = fmaxf(acc[0] * cd + bv0.x, 0.0f);
    h0.y = fmaxf(acc[1] * cd + bv0.y, 0.0f);
    h0.z = fmaxf(acc[2] * cd + bv0.z, 0.0f);
    h0.w = fmaxf(acc[3] * cd + bv0.w, 0.0f);
    h1.x = fmaxf(acc[4] * cd + bv1.x, 0.0f);
    h1.y = fmaxf(acc[5] * cd + bv1.y, 0.0f);
    h1.z = fmaxf(acc[6] * cd + bv1.z, 0.0f);
    h1.w = fmaxf(acc[7] * cd + bv1.w, 0.0f);
    if (lane < 8) {
      *((float4*)&hs[wslot][8 * f]) = h0;
      *((float4*)&hs[wslot][8 * f + 4]) = h1;
    }
    // same-wave LDS RAW: in-order DS pipe, no barrier needed
    float acc2 = 0.0f;
#pragma unroll
    for (int k4 = 0; k4 < 16; k4++) {
      float4 hv = *((const float4*)&hs[wslot][4 * k4]);
      float4 w = *((const float4*)&WsT[lane * 64 + ((k4 ^ (lane & 7)) << 2)]);
      acc2 += hv.x * w.x + hv.y * w.y + hv.z * w.z + hv.w * w.w;
    }
    Y2[(size_t)wid * 64 + lane] = __float2half(csrc[wid] * acc2);
  }
}

// ---------------------------------------------------------------------------
// Final aggregation + epilogue into z (fp32 output), grid-stride persistent.
// MODE 0: z = relu(...)
// MODE 1: z -= relu(...), and emit uv[node] = {z.Wc_top(2), z.Wc_bot(2)}
// ---------------------------------------------------------------------------
template <int MODE>
__global__ __launch_bounds__(256) void gather_fin(
    const __half* __restrict__ Y2, const int* __restrict__ offs,
    const int* __restrict__ degv, const int* __restrict__ srclist,
    const float* __restrict__ b1, float* __restrict__ z,
    float* __restrict__ uv, const float* __restrict__ Wc) {
  __shared__ float Wcs[256];
  if (MODE == 1) {
    Wcs[threadIdx.x] = Wc[threadIdx.x];
    __syncthreads();
  }
  int lane = threadIdx.x & 63;
  int wslot = threadIdx.x >> 6;
  int f = lane & 7, q = lane >> 3;
  float4 bv0 = ((const float4*)b1)[2 * f];
  float4 bv1 = ((const float4*)b1)[2 * f + 1];
  for (int wid = blockIdx.x * 4 + wslot; wid < N_NODES; wid += AGG_STRIDE) {
    int beg = offs[wid];
    int deg = degv[wid];
    float acc[8];
    agg_oct(Y2, beg, deg, srclist, lane, f, q, acc);
    float cd = deg > 0 ? rsqrtf((float)deg) : 0.0f;
    float v[8];
    v[0] = fmaxf(acc[0] * cd + bv0.x, 0.0f);
    v[1] = fmaxf(acc[1] * cd + bv0.y, 0.0f);
    v[2] = fmaxf(acc[2] * cd + bv0.z, 0.0f);
    v[3] = fmaxf(acc[3] * cd + bv0.w, 0.0f);
    v[4] = fmaxf(acc[4] * cd + bv1.x, 0.0f);
    v[5] = fmaxf(acc[5] * cd + bv1.y, 0.0f);
    v[6] = fmaxf(acc[6] * cd + bv1.z, 0.0f);
    v[7] = fmaxf(acc[7] * cd + bv1.w, 0.0f);
    float* zrow = z + (size_t)wid * 64 + 8 * f;
    if (MODE == 0) {
      if (lane < 8) {
        *((float4*)zrow) = make_float4(v[0], v[1], v[2], v[3]);
        *((float4*)(zrow + 4)) = make_float4(v[4], v[5], v[6], v[7]);
      }
    } else {
      float4 zo0 = *((const float4*)zrow);
      float4 zo1 = *((const float4*)(zrow + 4));
      float r[8];
      r[0] = zo0.x - v[0]; r[1] = zo0.y - v[1];
      r[2] = zo0.z - v[2]; r[3] = zo0.w - v[3];
      r[4] = zo1.x - v[4]; r[5] = zo1.y - v[5];
      r[6] = zo1.z - v[6]; r[7] = zo1.w - v[7];
      if (lane < 8) {
        *((float4*)zrow) = make_float4(r[0], r[1], r[2], r[3]);
        *((float4*)(zrow + 4)) = make_float4(r[4], r[5], r[6], r[7]);
      }
      float pu0 = 0.0f, pu1 = 0.0f, pv0 = 0.0f, pv1 = 0.0f;
#pragma unroll
      for (int i = 0; i < 8; i++) {
        int j = 8 * f + i;
        pu0 += r[i] * Wcs[j * 2 + 0];
        pu1 += r[i] * Wcs[j * 2 + 1];
        pv0 += r[i] * Wcs[(64 + j) * 2 + 0];
        pv1 += r[i] * Wcs[(64 + j) * 2 + 1];
      }
#pragma unroll
      for (int o = 1; o < 8; o <<= 1) {
        pu0 += __shfl_xor(pu0, o);
        pu1 += __shfl_xor(pu1, o);
        pv0 += __shfl_xor(pv0, o);
        pv1 += __shfl_xor(pv1, o);
      }
      if (lane == 0) {
        float4 o4 = make_float4(pu0, pu1, pv0, pv1);
        *((float4*)(uv + (size_t)wid * 4)) = o4;
      }
    }
  }
}

// ---------------------------------------------------------------------------
// probs[e] = sigmoid(u(s) + v(d) + bc)  — factorized classifier
// ---------------------------------------------------------------------------
__global__ __launch_bounds__(256) void classify_kernel(
    const float* __restrict__ uv, const int* __restrict__ ei,
    const float* __restrict__ bc, float* __restrict__ out) {
  int e = blockIdx.x * 256 + threadIdx.x;
  if (e >= E_QQ) return;
  int s = ei[e];
  int d = ei[E_QQ + e];
  float4 us = *((const float4*)(uv + (size_t)s * 4));
  float4 vd = *((const float4*)(uv + (size_t)d * 4));
  float l0 = us.x + vd.z + bc[0];
  float l1 = us.y + vd.w + bc[1];
  float2 o;
  o.x = 1.0f / (1.0f + __expf(-l0));
  o.y = 1.0f / (1.0f + __expf(-l1));
  *((float2*)(out + (size_t)e * 2)) = o;
}

extern "C" void kernel_launch(void* const* d_in, const int* in_sizes, int n_in,
                              void* d_out, int out_size, void* d_ws,
                              size_t ws_size, hipStream_t stream) {
  const float* x   = (const float*)d_in[0];
  const float* W0p = (const float*)d_in[1];
  const float* b0p = (const float*)d_in[2];
  const float* W0n = (const float*)d_in[3];
  const float* b0n = (const float*)d_in[4];
  const float* W1p = (const float*)d_in[5];
  const float* b1p = (const float*)d_in[6];
  const float* W1n = (const float*)d_in[7];
  const float* b1n = (const float*)d_in[8];
  const float* Wc  = (const float*)d_in[9];
  const float* bc  = (const float*)d_in[10];
  const int* sp = (const int*)d_in[11];
  const int* dp = (const int*)d_in[12];
  const int* sn = (const int*)d_in[13];
  const int* dn = (const int*)d_in[14];
  const int* ei = (const int*)d_in[15];

  // workspace layout (~53 MB)
  float* csrc_p = (float*)d_ws;                       // N
  float* csrc_n = csrc_p + N_NODES;                   // N
  int* offs_p = (int*)(csrc_n + N_NODES);             // N
  int* deg_p  = offs_p + N_NODES;                     // N
  int* offs_n = deg_p + N_NODES;                      // N
  int* deg_n  = offs_n + N_NODES;                     // N
  float* uv   = (float*)(deg_n + N_NODES);            // 4N
  int* gcur   = (int*)(uv + 4 * N_NODES);             // 2*NBUCK (+pad)
  unsigned* bin_d = (unsigned*)(gcur + 2 * NBUCK + 2);       // NBUCK*BCAP
  unsigned* bin_s = bin_d + (size_t)NBUCK * BCAP;            // NBUCK*BCAP
  int* srclist = (int*)(bin_s + (size_t)NBUCK * BCAP);       // NBUCK*BCAP
  __half* A = (__half*)(srclist + (size_t)NBUCK * BCAP);     // N*64 fp16
  __half* B = A + (size_t)N_NODES * 64;                      // N*64 fp16

  float* z     = (float*)d_out;                   // N*64 fp32
  float* probs = z + (size_t)N_NODES * 64;        // E_Q*2 fp32

  int* gcur_d = gcur;
  int* gcur_s = gcur + NBUCK;

  const int gemmGrid = (N_NODES + 255) / 256;

  // ---- POS relation ----
  hipMemsetAsync(gcur, 0, 2 * NBUCK * sizeof(int), stream);
  bin_edges<<<P1_BLOCKS, 256, 0, stream>>>(sp, dp, gcur_d, gcur_s, bin_d, bin_s);
  build_tables<<<2 * NBUCK, 256, 0, stream>>>(bin_d, gcur_d, bin_s, gcur_s,
                                              offs_p, deg_p, srclist, csrc_p);
  gemm_in_h<<<gemmGrid, 256, 0, stream>>>(x, W0p, csrc_p, A);
  gather_mid<<<AGG_BLOCKS, 256, 0, stream>>>(A, offs_p, deg_p, srclist, b0p,
                                             csrc_p, W1p, B);
  gather_fin<0><<<AGG_BLOCKS, 256, 0, stream>>>(B, offs_p, deg_p, srclist, b1p,
                                                z, uv, Wc);

  // ---- NEG relation ---- (bins/srclist reused; pos consumers done)
  hipMemsetAsync(gcur, 0, 2 * NBUCK * sizeof(int), stream);
  bin_edges<<<P1_BLOCKS, 256, 0, stream>>>(sn, dn, gcur_d, gcur_s, bin_d, bin_s);
  build_tables<<<2 * NBUCK, 256, 0, stream>>>(bin_d, gcur_d, bin_s, gcur_s,
                                              offs_n, deg_n, srclist, csrc_n);
  gemm_in_h<<<gemmGrid, 256, 0, stream>>>(x, W0n, csrc_n, A);
  gather_mid<<<AGG_BLOCKS, 256, 0, stream>>>(A, offs_n, deg_n, srclist, b0n,
                                             csrc_n, W1n, B);
  gather_fin<1><<<AGG_BLOCKS, 256, 0, stream>>>(B, offs_n, deg_n, srclist, b1n,
                                                z, uv, Wc);

  // ---- classifier (factorized) ----
  classify_kernel<<<(E_QQ + 255) / 256, 256, 0, stream>>>(uv, ei, bc, probs);
}